// Round 6
// baseline (876.854 us; speedup 1.0000x reference)
//
#include <hip/hip_runtime.h>

typedef __attribute__((ext_vector_type(8))) short bf16x8;
typedef __attribute__((ext_vector_type(4))) float f32x4;

__device__ __forceinline__ float b2f(unsigned short u) {
    union { unsigned int i; float f; } x; x.i = ((unsigned int)u) << 16; return x.f;
}
__device__ __forceinline__ unsigned short f2b(float f) {
    union { float f; unsigned int i; } x; x.f = f;
    unsigned int r = x.i + 0x7fffu + ((x.i >> 16) & 1u);  // RNE
    return (unsigned short)(r >> 16);
}

// Partial Cox-de Boor exactly as the reference leaves it:
// cols 0-4 degree 3, col 5 degree 2, col 6 degree 1, col 7 degree 0.
// knots = [-1,-1,-1,-1,-0.6,-0.2,0.2,0.6,1,1,1,1]
__device__ __forceinline__ float kan_spline(float t, const float* cpf, float rwf) {
    float c3 = (t >= -1.0f && t < -0.6f) ? 1.0f : 0.0f;
    float c4 = (t >= -0.6f && t < -0.2f) ? 1.0f : 0.0f;
    float c5 = (t >= -0.2f && t <  0.2f) ? 1.0f : 0.0f;
    float c6 = (t >=  0.2f && t <  0.6f) ? 1.0f : 0.0f;
    float c7 = (t >=  0.6f && t <  1.0f) ? 1.0f : 0.0f;
    float d2 = (-0.6f - t) * 2.5f * c3;
    float d3 = (t + 1.0f) * 2.5f * c3 + (-0.2f - t) * 2.5f * c4;
    float d4 = (t + 0.6f) * 2.5f * c4 + ( 0.2f - t) * 2.5f * c5;
    float d5 = (t + 0.2f) * 2.5f * c5 + ( 0.6f - t) * 2.5f * c6;
    float d6 = (t - 0.2f) * 2.5f * c6 + ( 1.0f - t) * 2.5f * c7;
    float e1 = (-0.6f - t) * 2.5f  * d2;
    float e2 = (t + 1.0f) * 2.5f  * d2 + (-0.2f - t) * 1.25f * d3;
    float e3 = (t + 1.0f) * 1.25f * d3 + ( 0.2f - t) * 1.25f * d4;
    float e4 = (t + 0.6f) * 1.25f * d4 + ( 0.6f - t) * 1.25f * d5;
    float e5 = (t + 0.2f) * 1.25f * d5 + ( 1.0f - t) * 1.25f * d6;
    const float r12 = 1.0f / 1.2f;
    float f0 = (-0.6f - t) * 2.5f  * e1;
    float f1 = (t + 1.0f) * 2.5f  * e1 + (-0.2f - t) * 1.25f * e2;
    float f2 = (t + 1.0f) * 1.25f * e2 + ( 0.2f - t) * r12   * e3;
    float f3 = (t + 1.0f) * r12   * e3 + ( 0.6f - t) * r12   * e4;
    float f4 = (t + 0.6f) * r12   * e4 + ( 1.0f - t) * r12   * e5;
    float sp = f0*cpf[0] + f1*cpf[1] + f2*cpf[2] + f3*cpf[3] + f4*cpf[4]
             + e5*cpf[5] + d6*cpf[6] + c7*cpf[7];
    float v = sp * rwf;
    return fminf(fmaxf(v, -10.0f), 10.0f);
}

// per-row mean / rstd of x[1024,2048] f32, fp64 accumulate
__global__ void ln_stats_kernel(const float* __restrict__ x,
                                float* __restrict__ mu, float* __restrict__ rstd) {
    const int row = blockIdx.x;
    const float* p = x + (size_t)row * 2048 + threadIdx.x * 8;
    double s = 0.0, q = 0.0;
#pragma unroll
    for (int i = 0; i < 8; ++i) { float v = p[i]; s += v; q += (double)v * v; }
    for (int o = 32; o > 0; o >>= 1) { s += __shfl_down(s, o, 64); q += __shfl_down(q, o, 64); }
    __shared__ double shs[4], shq[4];
    const int lane = threadIdx.x & 63, w = threadIdx.x >> 6;
    if (lane == 0) { shs[w] = s; shq[w] = q; }
    __syncthreads();
    if (threadIdx.x == 0) {
        double S = shs[0] + shs[1] + shs[2] + shs[3];
        double Q = shq[0] + shq[1] + shq[2] + shq[3];
        double m = S / 2048.0;
        double var = Q / 2048.0 - m * m;
        mu[row] = (float)m;
        rstd[row] = (float)(1.0 / sqrt(var + 1e-5));
    }
}

// S[n] = sum_k W[n,k] (f32 W); one wave per row, 4 rows per block
__global__ void rowsum_kernel(const float* __restrict__ W,
                              float* __restrict__ S, int K) {
    const int lane = threadIdx.x & 63, w = threadIdx.x >> 6;
    const int row = blockIdx.x * 4 + w;
    const float* p = W + (size_t)row * K;
    double s = 0.0;
    for (int c = lane * 8; c < K; c += 512) {
#pragma unroll
        for (int i = 0; i < 8; ++i) s += p[c + i];
    }
    for (int o = 32; o > 0; o >>= 1) s += __shfl_down(s, o, 64);
    if (lane == 0) S[row] = (float)s;
}

// [R,C] f32 -> [R,2C] bf16 as [hi | lo]; one block per row, C = 2048
__global__ void split2_kernel(const float* __restrict__ src,
                              unsigned short* __restrict__ dst, int C) {
    const int r = blockIdx.x;
    const int c = threadIdx.x * 8;
    const float* p = src + (size_t)r * C + c;
    float4 u0 = ((const float4*)p)[0];
    float4 u1 = ((const float4*)p)[1];
    float v[8] = {u0.x, u0.y, u0.z, u0.w, u1.x, u1.y, u1.z, u1.w};
    unsigned short hi[8], lo[8];
#pragma unroll
    for (int i = 0; i < 8; ++i) {
        hi[i] = f2b(v[i]);
        lo[i] = f2b(v[i] - b2f(hi[i]));
    }
    unsigned short* d = dst + (size_t)r * 2 * C + c;
    *(uint4*)d = *(const uint4*)hi;
    *(uint4*)(d + C) = *(const uint4*)lo;
}

// flat f32 -> bf16, 8 el/thread
__global__ void cvt_kernel(const float* __restrict__ src,
                           unsigned short* __restrict__ dst) {
    const size_t i = ((size_t)blockIdx.x * 256 + threadIdx.x) * 8;
    float4 u0 = ((const float4*)(src + i))[0];
    float4 u1 = ((const float4*)(src + i))[1];
    float v[8] = {u0.x, u0.y, u0.z, u0.w, u1.x, u1.y, u1.z, u1.w};
    unsigned short t[8];
#pragma unroll
    for (int q = 0; q < 8; ++q) t[q] = f2b(v[q]);
    *(uint4*)(dst + i) = *(const uint4*)t;
}

// C[M=1024,N] = A[M,K] @ B[N,K]^T with fused epilogue. Register-prefetch
// pipelined K-loop, BK=64, LDS rows padded to 72 shorts.
// 256 threads, 4 waves 2x2, wave tile (BM/2)x(BN/2).
// EPI 0 (SPLIT): acc = Ahi*Bhi + Alo*Bhi + Ahi*Blo; A = f32 x staged hi/lo;
//        B: BPRE ? precomputed [hi|lo] bf16 rows (ldb=2K, lo at +K)
//                : f32 W staged hi/lo in-loop.
//        lin = rstd*(acc - mu*S1) + bias, KAN + NCT, bf16 out.
// EPI 1: A bf16 act; B: BPRE ? bf16 : f32-staged. lin=acc+bias, KAN+NCT, bf16.
// EPI 2: same as EPI 1 but plain bias epilogue, f32 out.
template <int BM, int BN, int EPI, bool BPRE>
__global__ __launch_bounds__(256, 4)
void gemm_kan(const void* __restrict__ Aptr,
              const void* __restrict__ Bptr,
              const float* __restrict__ bias,
              const float* __restrict__ cp,
              const float* __restrict__ rw,
              const float* __restrict__ mu,
              const float* __restrict__ rstd,
              const float* __restrict__ S1,
              void* __restrict__ outp,
              int N, int K, int lda, int ldb)
{
    constexpr int BK = 64;
    constexpr int LDP = 72;
    constexpr bool SPLIT = (EPI == 0);
    constexpr int WM = BM / 2, WN = BN / 2;
    constexpr int FM = WM / 16, FN = WN / 16;
    constexpr int OFF_B  = BM * LDP;
    constexpr int OFF_LO = (BM + BN) * LDP;
    constexpr int NBQ = BN / 64;               // f32-B staging passes

    __shared__ unsigned short lds[(SPLIT ? 2 : 1) * (BM + BN) * LDP];

    const int tid  = threadIdx.x;
    const int lane = tid & 63;
    const int wid  = tid >> 6;
    const int bm = blockIdx.y * BM;
    const int bn = blockIdx.x * BN;
    const int wmo = (wid >> 1) * WM;
    const int wno = (wid & 1) * WN;
    const int fr = lane & 15;
    const int kq = lane >> 4;

    const int sfr = tid >> 2;          // f32 staging row (64 rows)
    const int sfc = (tid & 3) << 4;    // f32 staging col (16 f32)
    const int sar = tid >> 3;          // bf16 staging row (32 rows/pass)
    const int sac = (tid & 7) << 3;    // bf16 staging col (8 shorts)

    float rBf[NBQ][16];                // prefetch: f32 B
    uint4 rBb[SPLIT ? 4 : 2];          // prefetch: bf16 B (2 passes; +lo)
    float rAf[16];                     // prefetch: f32 A (split)
    uint4 rAb[2];                      // prefetch: bf16 A

    auto load_tiles = [&](int k) {
        if constexpr (BPRE) {
            const unsigned short* Bb = (const unsigned short*)Bptr;
#pragma unroll
            for (int q = 0; q < 2; ++q) {
                const size_t base = (size_t)(bn + q * 32 + sar) * ldb + k + sac;
                rBb[q] = *(const uint4*)(Bb + base);
                if constexpr (SPLIT)
                    rBb[2 + q] = *(const uint4*)(Bb + base + K);
            }
        } else {
            const float* Bf = (const float*)Bptr;
#pragma unroll
            for (int q = 0; q < NBQ; ++q) {
                const float* g = Bf + (size_t)(bn + q * 64 + sfr) * ldb + k + sfc;
                *(float4*)&rBf[q][0]  = ((const float4*)g)[0];
                *(float4*)&rBf[q][4]  = ((const float4*)g)[1];
                *(float4*)&rBf[q][8]  = ((const float4*)g)[2];
                *(float4*)&rBf[q][12] = ((const float4*)g)[3];
            }
        }
        if constexpr (SPLIT) {
            const float* g = (const float*)Aptr + (size_t)(bm + sfr) * lda + k + sfc;
            *(float4*)&rAf[0]  = ((const float4*)g)[0];
            *(float4*)&rAf[4]  = ((const float4*)g)[1];
            *(float4*)&rAf[8]  = ((const float4*)g)[2];
            *(float4*)&rAf[12] = ((const float4*)g)[3];
        } else {
            const unsigned short* Ab = (const unsigned short*)Aptr;
            rAb[0] = *(const uint4*)(Ab + (size_t)(bm + sar) * lda + k + sac);
            rAb[1] = *(const uint4*)(Ab + (size_t)(bm + 32 + sar) * lda + k + sac);
        }
    };

    auto stage_lds = [&]() {
        if constexpr (BPRE) {
#pragma unroll
            for (int q = 0; q < 2; ++q) {
                const int r = q * 32 + sar;
                *(uint4*)&lds[OFF_B + r * LDP + sac] = rBb[q];
                if constexpr (SPLIT)
                    *(uint4*)&lds[OFF_B + OFF_LO + r * LDP + sac] = rBb[2 + q];
            }
        } else {
#pragma unroll
            for (int q = 0; q < NBQ; ++q) {
                unsigned short hi[16], lo[16];
#pragma unroll
                for (int i = 0; i < 16; ++i) {
                    hi[i] = f2b(rBf[q][i]);
                    if (SPLIT) lo[i] = f2b(rBf[q][i] - b2f(hi[i]));
                }
                unsigned short* d = &lds[OFF_B + (q * 64 + sfr) * LDP + sfc];
                ((uint4*)d)[0] = *(const uint4*)&hi[0];
                ((uint4*)d)[1] = *(const uint4*)&hi[8];
                if (SPLIT) {
                    unsigned short* dl = d + OFF_LO;
                    ((uint4*)dl)[0] = *(const uint4*)&lo[0];
                    ((uint4*)dl)[1] = *(const uint4*)&lo[8];
                }
            }
        }
        if constexpr (SPLIT) {
            unsigned short hi[16], lo[16];
#pragma unroll
            for (int i = 0; i < 16; ++i) {
                hi[i] = f2b(rAf[i]);
                lo[i] = f2b(rAf[i] - b2f(hi[i]));
            }
            unsigned short* d = &lds[sfr * LDP + sfc];
            ((uint4*)d)[0] = *(const uint4*)&hi[0];
            ((uint4*)d)[1] = *(const uint4*)&hi[8];
            unsigned short* dl = d + OFF_LO;
            ((uint4*)dl)[0] = *(const uint4*)&lo[0];
            ((uint4*)dl)[1] = *(const uint4*)&lo[8];
        } else {
            *(uint4*)&lds[sar * LDP + sac] = rAb[0];
            *(uint4*)&lds[(32 + sar) * LDP + sac] = rAb[1];
        }
    };

    f32x4 acc[FM][FN] = {};

    load_tiles(0);
    for (int k0 = 0; k0 < K; k0 += BK) {
        stage_lds();
        __syncthreads();
        if (k0 + BK < K) load_tiles(k0 + BK);
#pragma unroll
        for (int s = 0; s < 2; ++s) {
            const int cc = (s * 4 + kq) << 3;
            bf16x8 aF[FM], bF[FN];
#pragma unroll
            for (int i = 0; i < FM; ++i)
                aF[i] = *(const bf16x8*)&lds[(wmo + i * 16 + fr) * LDP + cc];
#pragma unroll
            for (int j = 0; j < FN; ++j)
                bF[j] = *(const bf16x8*)&lds[OFF_B + (wno + j * 16 + fr) * LDP + cc];
#pragma unroll
            for (int i = 0; i < FM; ++i)
#pragma unroll
                for (int j = 0; j < FN; ++j)
                    acc[i][j] = __builtin_amdgcn_mfma_f32_16x16x32_bf16(aF[i], bF[j], acc[i][j], 0, 0, 0);
            if constexpr (SPLIT) {
                bf16x8 aL[FM], bL[FN];
#pragma unroll
                for (int i = 0; i < FM; ++i)
                    aL[i] = *(const bf16x8*)&lds[OFF_LO + (wmo + i * 16 + fr) * LDP + cc];
#pragma unroll
                for (int i = 0; i < FM; ++i)
#pragma unroll
                    for (int j = 0; j < FN; ++j)
                        acc[i][j] = __builtin_amdgcn_mfma_f32_16x16x32_bf16(aL[i], bF[j], acc[i][j], 0, 0, 0);
#pragma unroll
                for (int j = 0; j < FN; ++j)
                    bL[j] = *(const bf16x8*)&lds[OFF_LO + OFF_B + (wno + j * 16 + fr) * LDP + cc];
#pragma unroll
                for (int i = 0; i < FM; ++i)
#pragma unroll
                    for (int j = 0; j < FN; ++j)
                        acc[i][j] = __builtin_amdgcn_mfma_f32_16x16x32_bf16(aF[i], bL[j], acc[i][j], 0, 0, 0);
            }
        }
        __syncthreads();
    }

    // ---- epilogue: C layout col = lane&15, row = (lane>>4)*4 + reg ----
    const int rowg = (lane >> 4) * 4;
#pragma unroll
    for (int j = 0; j < FN; ++j) {
        const int n = bn + wno + j * 16 + fr;
        const float bs = bias[n];
        float cpf[8], rwf = 0.0f, s1 = 0.0f;
        if (EPI < 2) {
#pragma unroll
            for (int q = 0; q < 8; ++q) cpf[q] = cp[(size_t)n * 9 + q];
            rwf = rw[n];
        }
        if (EPI == 0) s1 = S1[n];
        const int s = n & 7;  // generator slot: {0,1}->sx, {2,3}->sy, {4..7}->identity
#pragma unroll
        for (int i = 0; i < FM; ++i) {
            const int m0 = bm + wmo + i * 16 + rowg;
#pragma unroll
            for (int r = 0; r < 4; ++r) {
                const int m = m0 + r;
                float v = acc[i][j][r];
                if (EPI == 0) v = (v - mu[m] * s1) * rstd[m] + bs;
                else          v += bs;
                if (EPI < 2) {
                    v = kan_spline(tanhf(v), cpf, rwf);
                    float p = __shfl_xor(v, 1, 64);  // partner col n^1 lives in lane^1
                    p = fminf(fmaxf(p, -1.0f), 1.0f);
                    if (s < 4) v += ((s == 2) ? -0.05f : 0.05f) * p;
                }
                if (EPI == 2) ((float*)outp)[(size_t)m * N + n] = v;
                else ((unsigned short*)outp)[(size_t)m * N + n] = f2b(v);
            }
        }
    }
}

extern "C" void kernel_launch(void* const* d_in, const int* in_sizes, int n_in,
                              void* d_out, int out_size, void* d_ws, size_t ws_size,
                              hipStream_t stream) {
    const float* x    = (const float*)d_in[0];
    const float* W1   = (const float*)d_in[1];
    const float* b1   = (const float*)d_in[2];
    const float* cp1  = (const float*)d_in[3];
    const float* rw1  = (const float*)d_in[4];
    const float* W2   = (const float*)d_in[5];
    const float* b2   = (const float*)d_in[6];
    const float* cp2  = (const float*)d_in[7];
    const float* rw2  = (const float*)d_in[8];
    const float* W3   = (const float*)d_in[9];
    const float* b3   = (const float*)d_in[10];
    const float* cp3  = (const float*)d_in[11];
    const float* rw3  = (const float*)d_in[12];
    const float* Wout = (const float*)d_in[13];
    const float* bout = (const float*)d_in[14];

    char* ws = (char*)d_ws;
    float* mu   = (float*)(ws);                  // 1024 f32
    float* rstd = (float*)(ws + 4096);           // 1024 f32
    float* S1   = (float*)(ws + 8192);           // 4096 f32
    unsigned short* A2 = (unsigned short*)(ws + 32768);              // 1024x4096 bf16
    unsigned short* A3 = (unsigned short*)(ws + 32768 + 8388608);    // 1024x4096 bf16
    unsigned short* A4 = A2;                     // 1024x2048 bf16 (A2 dead after L2)
    unsigned short* Wb = (unsigned short*)(ws + 32768 + 2 * 8388608); // 33.55 MB shared W region
    const size_t WS_NEED = 32768 + 2 * 8388608 + 33554432;           // 50.4 MB

    ln_stats_kernel<<<1024, 256, 0, stream>>>(x, mu, rstd);
    rowsum_kernel<<<1024, 256, 0, stream>>>(W1, S1, 2048);

    if (ws_size >= WS_NEED) {
        // pre-converted-weights path
        split2_kernel<<<4096, 256, 0, stream>>>(W1, Wb, 2048);       // [hi|lo], ldb=4096
        gemm_kan<64, 64, 0, true><<<dim3(64, 16), 256, 0, stream>>>(
            x, Wb, b1, cp1, rw1, mu, rstd, S1, A2, 4096, 2048, 2048, 4096);
        cvt_kernel<<<8192, 256, 0, stream>>>(W2, Wb);                // 4096x4096 bf16
        gemm_kan<64, 64, 1, true><<<dim3(64, 16), 256, 0, stream>>>(
            A2, Wb, b2, cp2, rw2, nullptr, nullptr, nullptr, A3, 4096, 4096, 4096, 4096);
        cvt_kernel<<<4096, 256, 0, stream>>>(W3, Wb);                // 2048x4096 bf16
        gemm_kan<64, 64, 1, true><<<dim3(32, 16), 256, 0, stream>>>(
            A3, Wb, b3, cp3, rw3, nullptr, nullptr, nullptr, A4, 2048, 4096, 4096, 4096);
        cvt_kernel<<<2048, 256, 0, stream>>>(Wout, Wb);              // 2048x2048 bf16
        gemm_kan<64, 64, 2, true><<<dim3(32, 16), 256, 0, stream>>>(
            A4, Wb, bout, nullptr, nullptr, nullptr, nullptr, nullptr, d_out, 2048, 2048, 2048, 2048);
    } else {
        // fallback: in-loop f32->bf16 staging (round-5 numerics, new tiles)
        gemm_kan<64, 64, 0, false><<<dim3(64, 16), 256, 0, stream>>>(
            x, W1, b1, cp1, rw1, mu, rstd, S1, A2, 4096, 2048, 2048, 2048);
        gemm_kan<64, 64, 1, false><<<dim3(64, 16), 256, 0, stream>>>(
            A2, W2, b2, cp2, rw2, nullptr, nullptr, nullptr, A3, 4096, 4096, 4096, 4096);
        gemm_kan<64, 64, 1, false><<<dim3(32, 16), 256, 0, stream>>>(
            A3, W3, b3, cp3, rw3, nullptr, nullptr, nullptr, A4, 2048, 4096, 4096, 4096);
        gemm_kan<64, 64, 2, false><<<dim3(32, 16), 256, 0, stream>>>(
            A4, Wout, bout, nullptr, nullptr, nullptr, nullptr, nullptr, d_out, 2048, 2048, 2048, 2048);
    }
}

// Round 7
// 873.320 us; speedup vs baseline: 1.0040x; 1.0040x over previous
//
#include <hip/hip_runtime.h>

typedef __attribute__((ext_vector_type(8))) short bf16x8;
typedef __attribute__((ext_vector_type(4))) float f32x4;

__device__ __forceinline__ float b2f(unsigned short u) {
    union { unsigned int i; float f; } x; x.i = ((unsigned int)u) << 16; return x.f;
}
__device__ __forceinline__ unsigned short f2b(float f) {
    union { float f; unsigned int i; } x; x.f = f;
    unsigned int r = x.i + 0x7fffu + ((x.i >> 16) & 1u);  // RNE
    return (unsigned short)(r >> 16);
}

// Partial Cox-de Boor exactly as the reference leaves it:
// cols 0-4 degree 3, col 5 degree 2, col 6 degree 1, col 7 degree 0.
// knots = [-1,-1,-1,-1,-0.6,-0.2,0.2,0.6,1,1,1,1]
__device__ __forceinline__ float kan_spline(float t, const float* cpf, float rwf) {
    float c3 = (t >= -1.0f && t < -0.6f) ? 1.0f : 0.0f;
    float c4 = (t >= -0.6f && t < -0.2f) ? 1.0f : 0.0f;
    float c5 = (t >= -0.2f && t <  0.2f) ? 1.0f : 0.0f;
    float c6 = (t >=  0.2f && t <  0.6f) ? 1.0f : 0.0f;
    float c7 = (t >=  0.6f && t <  1.0f) ? 1.0f : 0.0f;
    float d2 = (-0.6f - t) * 2.5f * c3;
    float d3 = (t + 1.0f) * 2.5f * c3 + (-0.2f - t) * 2.5f * c4;
    float d4 = (t + 0.6f) * 2.5f * c4 + ( 0.2f - t) * 2.5f * c5;
    float d5 = (t + 0.2f) * 2.5f * c5 + ( 0.6f - t) * 2.5f * c6;
    float d6 = (t - 0.2f) * 2.5f * c6 + ( 1.0f - t) * 2.5f * c7;
    float e1 = (-0.6f - t) * 2.5f  * d2;
    float e2 = (t + 1.0f) * 2.5f  * d2 + (-0.2f - t) * 1.25f * d3;
    float e3 = (t + 1.0f) * 1.25f * d3 + ( 0.2f - t) * 1.25f * d4;
    float e4 = (t + 0.6f) * 1.25f * d4 + ( 0.6f - t) * 1.25f * d5;
    float e5 = (t + 0.2f) * 1.25f * d5 + ( 1.0f - t) * 1.25f * d6;
    const float r12 = 1.0f / 1.2f;
    float f0 = (-0.6f - t) * 2.5f  * e1;
    float f1 = (t + 1.0f) * 2.5f  * e1 + (-0.2f - t) * 1.25f * e2;
    float f2 = (t + 1.0f) * 1.25f * e2 + ( 0.2f - t) * r12   * e3;
    float f3 = (t + 1.0f) * r12   * e3 + ( 0.6f - t) * r12   * e4;
    float f4 = (t + 0.6f) * r12   * e4 + ( 1.0f - t) * r12   * e5;
    float sp = f0*cpf[0] + f1*cpf[1] + f2*cpf[2] + f3*cpf[3] + f4*cpf[4]
             + e5*cpf[5] + d6*cpf[6] + c7*cpf[7];
    float v = sp * rwf;
    return fminf(fmaxf(v, -10.0f), 10.0f);
}

// per-row mean / rstd of x[1024,2048] f32, fp64 accumulate
__global__ void ln_stats_kernel(const float* __restrict__ x,
                                float* __restrict__ mu, float* __restrict__ rstd) {
    const int row = blockIdx.x;
    const float* p = x + (size_t)row * 2048 + threadIdx.x * 8;
    double s = 0.0, q = 0.0;
#pragma unroll
    for (int i = 0; i < 8; ++i) { float v = p[i]; s += v; q += (double)v * v; }
    for (int o = 32; o > 0; o >>= 1) { s += __shfl_down(s, o, 64); q += __shfl_down(q, o, 64); }
    __shared__ double shs[4], shq[4];
    const int lane = threadIdx.x & 63, w = threadIdx.x >> 6;
    if (lane == 0) { shs[w] = s; shq[w] = q; }
    __syncthreads();
    if (threadIdx.x == 0) {
        double S = shs[0] + shs[1] + shs[2] + shs[3];
        double Q = shq[0] + shq[1] + shq[2] + shq[3];
        double m = S / 2048.0;
        double var = Q / 2048.0 - m * m;
        mu[row] = (float)m;
        rstd[row] = (float)(1.0 / sqrt(var + 1e-5));
    }
}

// S[n] = sum_k W[n,k] (f32 W); one wave per row, 4 rows per block
__global__ void rowsum_kernel(const float* __restrict__ W,
                              float* __restrict__ S, int K) {
    const int lane = threadIdx.x & 63, w = threadIdx.x >> 6;
    const int row = blockIdx.x * 4 + w;
    const float* p = W + (size_t)row * K;
    double s = 0.0;
    for (int c = lane * 8; c < K; c += 512) {
#pragma unroll
        for (int i = 0; i < 8; ++i) s += p[c + i];
    }
    for (int o = 32; o > 0; o >>= 1) s += __shfl_down(s, o, 64);
    if (lane == 0) S[row] = (float)s;
}

// [R,C] f32 -> [R,2C] bf16 as [hi | lo]; one block per row, C = 2048
__global__ void split2_kernel(const float* __restrict__ src,
                              unsigned short* __restrict__ dst, int C) {
    const int r = blockIdx.x;
    const int c = threadIdx.x * 8;
    const float* p = src + (size_t)r * C + c;
    float4 u0 = ((const float4*)p)[0];
    float4 u1 = ((const float4*)p)[1];
    float v[8] = {u0.x, u0.y, u0.z, u0.w, u1.x, u1.y, u1.z, u1.w};
    unsigned short hi[8], lo[8];
#pragma unroll
    for (int i = 0; i < 8; ++i) {
        hi[i] = f2b(v[i]);
        lo[i] = f2b(v[i] - b2f(hi[i]));
    }
    unsigned short* d = dst + (size_t)r * 2 * C + c;
    *(uint4*)d = *(const uint4*)hi;
    *(uint4*)(d + C) = *(const uint4*)lo;
}

// flat f32 -> bf16, 8 el/thread
__global__ void cvt_kernel(const float* __restrict__ src,
                           unsigned short* __restrict__ dst) {
    const size_t i = ((size_t)blockIdx.x * 256 + threadIdx.x) * 8;
    float4 u0 = ((const float4*)(src + i))[0];
    float4 u1 = ((const float4*)(src + i))[1];
    float v[8] = {u0.x, u0.y, u0.z, u0.w, u1.x, u1.y, u1.z, u1.w};
    unsigned short t[8];
#pragma unroll
    for (int q = 0; q < 8; ++q) t[q] = f2b(v[q]);
    *(uint4*)(dst + i) = *(const uint4*)t;
}

// C[M=1024,N] = A[M,K] @ B[N,K]^T with fused epilogue. Register-prefetch
// pipelined K-loop, BK=64, LDS rows padded to 72 shorts.
// 256 threads, 4 waves 2x2, wave tile (BM/2)x(BN/2).
// NOTE: __launch_bounds__(256,2) — NOT (256,4): the 2nd arg is a hard VGPR
// cap (512/min_waves); 4 forced a 36-VGPR allocation and spilled the
// prefetch arrays to scratch (242 MB WRITE_SIZE, round 6). With 2, the
// kernel sits at ~56-72 VGPR and residency is LDS/grid-limited instead.
// EPI 0 (SPLIT): acc = Ahi*Bhi + Alo*Bhi + Ahi*Blo; A = f32 x staged hi/lo;
//        B: BPRE ? precomputed [hi|lo] bf16 rows (ldb=2K, lo at +K)
//                : f32 W staged hi/lo in-loop.
//        lin = rstd*(acc - mu*S1) + bias, KAN + NCT, bf16 out.
// EPI 1: A bf16 act; B: BPRE ? bf16 : f32-staged. lin=acc+bias, KAN+NCT, bf16.
// EPI 2: same as EPI 1 but plain bias epilogue, f32 out.
template <int BM, int BN, int EPI, bool BPRE>
__global__ __launch_bounds__(256, 2)
void gemm_kan(const void* __restrict__ Aptr,
              const void* __restrict__ Bptr,
              const float* __restrict__ bias,
              const float* __restrict__ cp,
              const float* __restrict__ rw,
              const float* __restrict__ mu,
              const float* __restrict__ rstd,
              const float* __restrict__ S1,
              void* __restrict__ outp,
              int N, int K, int lda, int ldb)
{
    constexpr int BK = 64;
    constexpr int LDP = 72;
    constexpr bool SPLIT = (EPI == 0);
    constexpr int WM = BM / 2, WN = BN / 2;
    constexpr int FM = WM / 16, FN = WN / 16;
    constexpr int OFF_B  = BM * LDP;
    constexpr int OFF_LO = (BM + BN) * LDP;
    constexpr int NBQ = BN / 64;               // f32-B staging passes

    __shared__ unsigned short lds[(SPLIT ? 2 : 1) * (BM + BN) * LDP];

    const int tid  = threadIdx.x;
    const int lane = tid & 63;
    const int wid  = tid >> 6;
    const int bm = blockIdx.y * BM;
    const int bn = blockIdx.x * BN;
    const int wmo = (wid >> 1) * WM;
    const int wno = (wid & 1) * WN;
    const int fr = lane & 15;
    const int kq = lane >> 4;

    const int sfr = tid >> 2;          // f32 staging row (64 rows)
    const int sfc = (tid & 3) << 4;    // f32 staging col (16 f32)
    const int sar = tid >> 3;          // bf16 staging row (32 rows/pass)
    const int sac = (tid & 7) << 3;    // bf16 staging col (8 shorts)

    float rBf[NBQ][16];                // prefetch: f32 B
    uint4 rBb[SPLIT ? 4 : 2];          // prefetch: bf16 B (2 passes; +lo)
    float rAf[16];                     // prefetch: f32 A (split)
    uint4 rAb[2];                      // prefetch: bf16 A

    auto load_tiles = [&](int k) {
        if constexpr (BPRE) {
            const unsigned short* Bb = (const unsigned short*)Bptr;
#pragma unroll
            for (int q = 0; q < 2; ++q) {
                const size_t base = (size_t)(bn + q * 32 + sar) * ldb + k + sac;
                rBb[q] = *(const uint4*)(Bb + base);
                if constexpr (SPLIT)
                    rBb[2 + q] = *(const uint4*)(Bb + base + K);
            }
        } else {
            const float* Bf = (const float*)Bptr;
#pragma unroll
            for (int q = 0; q < NBQ; ++q) {
                const float* g = Bf + (size_t)(bn + q * 64 + sfr) * ldb + k + sfc;
                *(float4*)&rBf[q][0]  = ((const float4*)g)[0];
                *(float4*)&rBf[q][4]  = ((const float4*)g)[1];
                *(float4*)&rBf[q][8]  = ((const float4*)g)[2];
                *(float4*)&rBf[q][12] = ((const float4*)g)[3];
            }
        }
        if constexpr (SPLIT) {
            const float* g = (const float*)Aptr + (size_t)(bm + sfr) * lda + k + sfc;
            *(float4*)&rAf[0]  = ((const float4*)g)[0];
            *(float4*)&rAf[4]  = ((const float4*)g)[1];
            *(float4*)&rAf[8]  = ((const float4*)g)[2];
            *(float4*)&rAf[12] = ((const float4*)g)[3];
        } else {
            const unsigned short* Ab = (const unsigned short*)Aptr;
            rAb[0] = *(const uint4*)(Ab + (size_t)(bm + sar) * lda + k + sac);
            rAb[1] = *(const uint4*)(Ab + (size_t)(bm + 32 + sar) * lda + k + sac);
        }
    };

    auto stage_lds = [&]() {
        if constexpr (BPRE) {
#pragma unroll
            for (int q = 0; q < 2; ++q) {
                const int r = q * 32 + sar;
                *(uint4*)&lds[OFF_B + r * LDP + sac] = rBb[q];
                if constexpr (SPLIT)
                    *(uint4*)&lds[OFF_B + OFF_LO + r * LDP + sac] = rBb[2 + q];
            }
        } else {
#pragma unroll
            for (int q = 0; q < NBQ; ++q) {
                unsigned short hi[16], lo[16];
#pragma unroll
                for (int i = 0; i < 16; ++i) {
                    hi[i] = f2b(rBf[q][i]);
                    if (SPLIT) lo[i] = f2b(rBf[q][i] - b2f(hi[i]));
                }
                unsigned short* d = &lds[OFF_B + (q * 64 + sfr) * LDP + sfc];
                ((uint4*)d)[0] = *(const uint4*)&hi[0];
                ((uint4*)d)[1] = *(const uint4*)&hi[8];
                if (SPLIT) {
                    unsigned short* dl = d + OFF_LO;
                    ((uint4*)dl)[0] = *(const uint4*)&lo[0];
                    ((uint4*)dl)[1] = *(const uint4*)&lo[8];
                }
            }
        }
        if constexpr (SPLIT) {
            unsigned short hi[16], lo[16];
#pragma unroll
            for (int i = 0; i < 16; ++i) {
                hi[i] = f2b(rAf[i]);
                lo[i] = f2b(rAf[i] - b2f(hi[i]));
            }
            unsigned short* d = &lds[sfr * LDP + sfc];
            ((uint4*)d)[0] = *(const uint4*)&hi[0];
            ((uint4*)d)[1] = *(const uint4*)&hi[8];
            unsigned short* dl = d + OFF_LO;
            ((uint4*)dl)[0] = *(const uint4*)&lo[0];
            ((uint4*)dl)[1] = *(const uint4*)&lo[8];
        } else {
            *(uint4*)&lds[sar * LDP + sac] = rAb[0];
            *(uint4*)&lds[(32 + sar) * LDP + sac] = rAb[1];
        }
    };

    f32x4 acc[FM][FN] = {};

    load_tiles(0);
    for (int k0 = 0; k0 < K; k0 += BK) {
        stage_lds();
        __syncthreads();
        if (k0 + BK < K) load_tiles(k0 + BK);
#pragma unroll
        for (int s = 0; s < 2; ++s) {
            const int cc = (s * 4 + kq) << 3;
            bf16x8 aF[FM], bF[FN];
#pragma unroll
            for (int i = 0; i < FM; ++i)
                aF[i] = *(const bf16x8*)&lds[(wmo + i * 16 + fr) * LDP + cc];
#pragma unroll
            for (int j = 0; j < FN; ++j)
                bF[j] = *(const bf16x8*)&lds[OFF_B + (wno + j * 16 + fr) * LDP + cc];
#pragma unroll
            for (int i = 0; i < FM; ++i)
#pragma unroll
                for (int j = 0; j < FN; ++j)
                    acc[i][j] = __builtin_amdgcn_mfma_f32_16x16x32_bf16(aF[i], bF[j], acc[i][j], 0, 0, 0);
            if constexpr (SPLIT) {
                bf16x8 aL[FM], bL[FN];
#pragma unroll
                for (int i = 0; i < FM; ++i)
                    aL[i] = *(const bf16x8*)&lds[OFF_LO + (wmo + i * 16 + fr) * LDP + cc];
#pragma unroll
                for (int i = 0; i < FM; ++i)
#pragma unroll
                    for (int j = 0; j < FN; ++j)
                        acc[i][j] = __builtin_amdgcn_mfma_f32_16x16x32_bf16(aL[i], bF[j], acc[i][j], 0, 0, 0);
#pragma unroll
                for (int j = 0; j < FN; ++j)
                    bL[j] = *(const bf16x8*)&lds[OFF_LO + OFF_B + (wno + j * 16 + fr) * LDP + cc];
#pragma unroll
                for (int i = 0; i < FM; ++i)
#pragma unroll
                    for (int j = 0; j < FN; ++j)
                        acc[i][j] = __builtin_amdgcn_mfma_f32_16x16x32_bf16(aF[i], bL[j], acc[i][j], 0, 0, 0);
            }
        }
        __syncthreads();
    }

    // ---- epilogue: C layout col = lane&15, row = (lane>>4)*4 + reg ----
    const int rowg = (lane >> 4) * 4;
#pragma unroll
    for (int j = 0; j < FN; ++j) {
        const int n = bn + wno + j * 16 + fr;
        const float bs = bias[n];
        float cpf[8], rwf = 0.0f, s1 = 0.0f;
        if (EPI < 2) {
#pragma unroll
            for (int q = 0; q < 8; ++q) cpf[q] = cp[(size_t)n * 9 + q];
            rwf = rw[n];
        }
        if (EPI == 0) s1 = S1[n];
        const int s = n & 7;  // generator slot: {0,1}->sx, {2,3}->sy, {4..7}->identity
#pragma unroll
        for (int i = 0; i < FM; ++i) {
            const int m0 = bm + wmo + i * 16 + rowg;
#pragma unroll
            for (int r = 0; r < 4; ++r) {
                const int m = m0 + r;
                float v = acc[i][j][r];
                if (EPI == 0) v = (v - mu[m] * s1) * rstd[m] + bs;
                else          v += bs;
                if (EPI < 2) {
                    v = kan_spline(tanhf(v), cpf, rwf);
                    float p = __shfl_xor(v, 1, 64);  // partner col n^1 lives in lane^1
                    p = fminf(fmaxf(p, -1.0f), 1.0f);
                    if (s < 4) v += ((s == 2) ? -0.05f : 0.05f) * p;
                }
                if (EPI == 2) ((float*)outp)[(size_t)m * N + n] = v;
                else ((unsigned short*)outp)[(size_t)m * N + n] = f2b(v);
            }
        }
    }
}

extern "C" void kernel_launch(void* const* d_in, const int* in_sizes, int n_in,
                              void* d_out, int out_size, void* d_ws, size_t ws_size,
                              hipStream_t stream) {
    const float* x    = (const float*)d_in[0];
    const float* W1   = (const float*)d_in[1];
    const float* b1   = (const float*)d_in[2];
    const float* cp1  = (const float*)d_in[3];
    const float* rw1  = (const float*)d_in[4];
    const float* W2   = (const float*)d_in[5];
    const float* b2   = (const float*)d_in[6];
    const float* cp2  = (const float*)d_in[7];
    const float* rw2  = (const float*)d_in[8];
    const float* W3   = (const float*)d_in[9];
    const float* b3   = (const float*)d_in[10];
    const float* cp3  = (const float*)d_in[11];
    const float* rw3  = (const float*)d_in[12];
    const float* Wout = (const float*)d_in[13];
    const float* bout = (const float*)d_in[14];

    char* ws = (char*)d_ws;
    float* mu   = (float*)(ws);                  // 1024 f32
    float* rstd = (float*)(ws + 4096);           // 1024 f32
    float* S1   = (float*)(ws + 8192);           // 4096 f32
    unsigned short* A2 = (unsigned short*)(ws + 32768);              // 1024x4096 bf16
    unsigned short* A3 = (unsigned short*)(ws + 32768 + 8388608);    // 1024x4096 bf16
    unsigned short* A4 = A2;                     // 1024x2048 bf16 (A2 dead after L2)
    unsigned short* Wb = (unsigned short*)(ws + 32768 + 2 * 8388608); // 33.55 MB shared W region
    const size_t WS_NEED = 32768 + 2 * 8388608 + 33554432;           // 50.4 MB

    ln_stats_kernel<<<1024, 256, 0, stream>>>(x, mu, rstd);
    rowsum_kernel<<<1024, 256, 0, stream>>>(W1, S1, 2048);

    if (ws_size >= WS_NEED) {
        // pre-converted-weights path
        split2_kernel<<<4096, 256, 0, stream>>>(W1, Wb, 2048);       // [hi|lo], ldb=4096
        gemm_kan<64, 64, 0, true><<<dim3(64, 16), 256, 0, stream>>>(
            x, Wb, b1, cp1, rw1, mu, rstd, S1, A2, 4096, 2048, 2048, 4096);
        cvt_kernel<<<8192, 256, 0, stream>>>(W2, Wb);                // 4096x4096 bf16
        gemm_kan<64, 64, 1, true><<<dim3(64, 16), 256, 0, stream>>>(
            A2, Wb, b2, cp2, rw2, nullptr, nullptr, nullptr, A3, 4096, 4096, 4096, 4096);
        cvt_kernel<<<4096, 256, 0, stream>>>(W3, Wb);                // 2048x4096 bf16
        gemm_kan<64, 64, 1, true><<<dim3(32, 16), 256, 0, stream>>>(
            A3, Wb, b3, cp3, rw3, nullptr, nullptr, nullptr, A4, 2048, 4096, 4096, 4096);
        cvt_kernel<<<2048, 256, 0, stream>>>(Wout, Wb);              // 2048x2048 bf16
        gemm_kan<64, 64, 2, true><<<dim3(32, 16), 256, 0, stream>>>(
            A4, Wb, bout, nullptr, nullptr, nullptr, nullptr, nullptr, d_out, 2048, 2048, 2048, 2048);
    } else {
        // fallback: in-loop f32->bf16 staging (round-5 numerics, new tiles)
        gemm_kan<64, 64, 0, false><<<dim3(64, 16), 256, 0, stream>>>(
            x, W1, b1, cp1, rw1, mu, rstd, S1, A2, 4096, 2048, 2048, 2048);
        gemm_kan<64, 64, 1, false><<<dim3(64, 16), 256, 0, stream>>>(
            A2, W2, b2, cp2, rw2, nullptr, nullptr, nullptr, A3, 4096, 4096, 4096, 4096);
        gemm_kan<64, 64, 1, false><<<dim3(32, 16), 256, 0, stream>>>(
            A3, W3, b3, cp3, rw3, nullptr, nullptr, nullptr, A4, 2048, 4096, 4096, 4096);
        gemm_kan<64, 64, 2, false><<<dim3(32, 16), 256, 0, stream>>>(
            A4, Wout, bout, nullptr, nullptr, nullptr, nullptr, nullptr, d_out, 2048, 2048, 2048, 2048);
    }
}

// Round 8
// 444.700 us; speedup vs baseline: 1.9718x; 1.9638x over previous
//
#include <hip/hip_runtime.h>

typedef __attribute__((ext_vector_type(8))) short bf16x8;
typedef __attribute__((ext_vector_type(4))) float f32x4;

__device__ __forceinline__ float b2f(unsigned short u) {
    union { unsigned int i; float f; } x; x.i = ((unsigned int)u) << 16; return x.f;
}
__device__ __forceinline__ unsigned short f2b(float f) {
    union { float f; unsigned int i; } x; x.f = f;
    unsigned int r = x.i + 0x7fffu + ((x.i >> 16) & 1u);  // RNE
    return (unsigned short)(r >> 16);
}

// Partial Cox-de Boor exactly as the reference leaves it:
// cols 0-4 degree 3, col 5 degree 2, col 6 degree 1, col 7 degree 0.
// knots = [-1,-1,-1,-1,-0.6,-0.2,0.2,0.6,1,1,1,1]
__device__ __forceinline__ float kan_spline(float t, const float* cpf, float rwf) {
    float c3 = (t >= -1.0f && t < -0.6f) ? 1.0f : 0.0f;
    float c4 = (t >= -0.6f && t < -0.2f) ? 1.0f : 0.0f;
    float c5 = (t >= -0.2f && t <  0.2f) ? 1.0f : 0.0f;
    float c6 = (t >=  0.2f && t <  0.6f) ? 1.0f : 0.0f;
    float c7 = (t >=  0.6f && t <  1.0f) ? 1.0f : 0.0f;
    float d2 = (-0.6f - t) * 2.5f * c3;
    float d3 = (t + 1.0f) * 2.5f * c3 + (-0.2f - t) * 2.5f * c4;
    float d4 = (t + 0.6f) * 2.5f * c4 + ( 0.2f - t) * 2.5f * c5;
    float d5 = (t + 0.2f) * 2.5f * c5 + ( 0.6f - t) * 2.5f * c6;
    float d6 = (t - 0.2f) * 2.5f * c6 + ( 1.0f - t) * 2.5f * c7;
    float e1 = (-0.6f - t) * 2.5f  * d2;
    float e2 = (t + 1.0f) * 2.5f  * d2 + (-0.2f - t) * 1.25f * d3;
    float e3 = (t + 1.0f) * 1.25f * d3 + ( 0.2f - t) * 1.25f * d4;
    float e4 = (t + 0.6f) * 1.25f * d4 + ( 0.6f - t) * 1.25f * d5;
    float e5 = (t + 0.2f) * 1.25f * d5 + ( 1.0f - t) * 1.25f * d6;
    const float r12 = 1.0f / 1.2f;
    float f0 = (-0.6f - t) * 2.5f  * e1;
    float f1 = (t + 1.0f) * 2.5f  * e1 + (-0.2f - t) * 1.25f * e2;
    float f2 = (t + 1.0f) * 1.25f * e2 + ( 0.2f - t) * r12   * e3;
    float f3 = (t + 1.0f) * r12   * e3 + ( 0.6f - t) * r12   * e4;
    float f4 = (t + 0.6f) * r12   * e4 + ( 1.0f - t) * r12   * e5;
    float sp = f0*cpf[0] + f1*cpf[1] + f2*cpf[2] + f3*cpf[3] + f4*cpf[4]
             + e5*cpf[5] + d6*cpf[6] + c7*cpf[7];
    float v = sp * rwf;
    return fminf(fmaxf(v, -10.0f), 10.0f);
}

// per-row mean / rstd of x[1024,2048] f32, fp64 accumulate
__global__ void ln_stats_kernel(const float* __restrict__ x,
                                float* __restrict__ mu, float* __restrict__ rstd) {
    const int row = blockIdx.x;
    const float* p = x + (size_t)row * 2048 + threadIdx.x * 8;
    double s = 0.0, q = 0.0;
#pragma unroll
    for (int i = 0; i < 8; ++i) { float v = p[i]; s += v; q += (double)v * v; }
    for (int o = 32; o > 0; o >>= 1) { s += __shfl_down(s, o, 64); q += __shfl_down(q, o, 64); }
    __shared__ double shs[4], shq[4];
    const int lane = threadIdx.x & 63, w = threadIdx.x >> 6;
    if (lane == 0) { shs[w] = s; shq[w] = q; }
    __syncthreads();
    if (threadIdx.x == 0) {
        double S = shs[0] + shs[1] + shs[2] + shs[3];
        double Q = shq[0] + shq[1] + shq[2] + shq[3];
        double m = S / 2048.0;
        double var = Q / 2048.0 - m * m;
        mu[row] = (float)m;
        rstd[row] = (float)(1.0 / sqrt(var + 1e-5));
    }
}

// S[n] = sum_k W[n,k] (f32 W); one wave per row, 4 rows per block
__global__ void rowsum_kernel(const float* __restrict__ W,
                              float* __restrict__ S, int K) {
    const int lane = threadIdx.x & 63, w = threadIdx.x >> 6;
    const int row = blockIdx.x * 4 + w;
    const float* p = W + (size_t)row * K;
    double s = 0.0;
    for (int c = lane * 8; c < K; c += 512) {
#pragma unroll
        for (int i = 0; i < 8; ++i) s += p[c + i];
    }
    for (int o = 32; o > 0; o >>= 1) s += __shfl_down(s, o, 64);
    if (lane == 0) S[row] = (float)s;
}

// [R,C] f32 -> [R,2C] bf16 as [hi | lo]; one block per row, C = 2048
__global__ void split2_kernel(const float* __restrict__ src,
                              unsigned short* __restrict__ dst, int C) {
    const int r = blockIdx.x;
    const int c = threadIdx.x * 8;
    const float* p = src + (size_t)r * C + c;
    float4 u0 = ((const float4*)p)[0];
    float4 u1 = ((const float4*)p)[1];
    float v[8] = {u0.x, u0.y, u0.z, u0.w, u1.x, u1.y, u1.z, u1.w};
    unsigned short hi[8], lo[8];
#pragma unroll
    for (int i = 0; i < 8; ++i) {
        hi[i] = f2b(v[i]);
        lo[i] = f2b(v[i] - b2f(hi[i]));
    }
    unsigned short* d = dst + (size_t)r * 2 * C + c;
    *(uint4*)d = *(const uint4*)hi;
    *(uint4*)(d + C) = *(const uint4*)lo;
}

// flat f32 -> bf16, 8 el/thread
__global__ void cvt_kernel(const float* __restrict__ src,
                           unsigned short* __restrict__ dst) {
    const size_t i = ((size_t)blockIdx.x * 256 + threadIdx.x) * 8;
    float4 u0 = ((const float4*)(src + i))[0];
    float4 u1 = ((const float4*)(src + i))[1];
    float v[8] = {u0.x, u0.y, u0.z, u0.w, u1.x, u1.y, u1.z, u1.w};
    unsigned short t[8];
#pragma unroll
    for (int q = 0; q < 8; ++q) t[q] = f2b(v[q]);
    *(uint4*)(dst + i) = *(const uint4*)t;
}

// C[1024 x Ncols] = A @ B^T fused with LN-fold / KAN / NCT epilogue.
// BM=BN=64, BK=64, LDP=72 padding; 4 waves 2x2; 8 MFMA(16x16x32)/iter/wave.
// !! NO lambdas, NO address-taken state: rounds 5-7 proved [&]-lambda capture
// of prefetch arrays pins them in scratch (VGPR 36, 242 MB spill WRITE).
// Straight-line body + named uint4 prefetch regs (round-4-clean codegen).
// BSRC 0: A,B pre-converted bf16; EPI 0 maps logical Ktot=6144 over
//         A=[xhi|xlo] (lda 4096), B=[Whi|Wlo] (ldb 4096):
//         seg0 hi*hi, seg1 lo*hi, seg2 hi*lo. Register prefetch pipeline.
// BSRC 1: A bf16, B f32 -> bf16 hi in-loop (fallback; no prefetch).
// BSRC 2: A f32 (x), B f32; both staged hi+lo, 3 MFMA groups (L1 fallback).
// EPI 0: lin = rstd*(acc - mu*S1) + bias, KAN+NCT, bf16 out.
// EPI 1: lin = acc + bias, KAN+NCT, bf16 out.   EPI 2: lin = acc+bias, f32.
template <int EPI, int BSRC>
__global__ __launch_bounds__(256, 2)
void gemm_kan(const void* __restrict__ Av, const void* __restrict__ Bv,
              const float* __restrict__ bias, const float* __restrict__ cp,
              const float* __restrict__ rw, const float* __restrict__ mu,
              const float* __restrict__ rstd, const float* __restrict__ S1,
              void* __restrict__ outp,
              int Nld, int n0, int Ktot, int lda, int ldb)
{
    constexpr int BM = 64, BN = 64, BK = 64, LDP = 72;
    constexpr bool SPL = (BSRC == 2);
    constexpr int OFF_B  = BM * LDP;
    constexpr int OFF_LO = (BM + BN) * LDP;
    __shared__ unsigned short lds[(SPL ? 2 : 1) * (BM + BN) * LDP];

    const int tid  = threadIdx.x;
    const int lane = tid & 63;
    const int wid  = tid >> 6;
    const int bm = blockIdx.x * BM;
    const int bn = blockIdx.y * BN;
    const int wmo = (wid >> 1) * 32;
    const int wno = (wid & 1) * 32;
    const int fr = lane & 15;
    const int kq = lane >> 4;
    const int sar = tid >> 3, sac = (tid & 7) << 3;   // bf16 staging coords
    const int sfr = tid >> 2, sfc = (tid & 3) << 4;   // f32 staging coords

    f32x4 acc[2][2] = {};

    // named prefetch registers (BSRC 0 only; dead-code-eliminated otherwise)
    uint4 pA0 = {}, pA1 = {}, pB0 = {}, pB1 = {};
    const unsigned short* Ab = (const unsigned short*)Av;
    const unsigned short* Bb = (const unsigned short*)Bv;
    const size_t a0 = (size_t)(bm + sar) * lda + sac;
    const size_t a1 = (size_t)(bm + 32 + sar) * lda + sac;
    const size_t b0 = (size_t)(bn + sar) * ldb + sac;
    const size_t b1 = (size_t)(bn + 32 + sar) * ldb + sac;
    if constexpr (BSRC == 0) {
        pA0 = *(const uint4*)(Ab + a0);
        pA1 = *(const uint4*)(Ab + a1);
        pB0 = *(const uint4*)(Bb + b0);
        pB1 = *(const uint4*)(Bb + b1);
    }

    for (int k0 = 0; k0 < Ktot; k0 += BK) {
        // ---- stage into LDS ----
        if constexpr (BSRC == 0) {
            *(uint4*)&lds[sar * LDP + sac] = pA0;
            *(uint4*)&lds[(32 + sar) * LDP + sac] = pA1;
            *(uint4*)&lds[OFF_B + sar * LDP + sac] = pB0;
            *(uint4*)&lds[OFF_B + (32 + sar) * LDP + sac] = pB1;
        } else {
            {   // B from f32
                const float* g = (const float*)Bv + (size_t)(bn + sfr) * ldb + k0 + sfc;
                float4 u0 = ((const float4*)g)[0];
                float4 u1 = ((const float4*)g)[1];
                float4 u2 = ((const float4*)g)[2];
                float4 u3 = ((const float4*)g)[3];
                float v[16] = {u0.x,u0.y,u0.z,u0.w, u1.x,u1.y,u1.z,u1.w,
                               u2.x,u2.y,u2.z,u2.w, u3.x,u3.y,u3.z,u3.w};
                unsigned short hi[16], lo[16];
#pragma unroll
                for (int i = 0; i < 16; ++i) {
                    hi[i] = f2b(v[i]);
                    if (SPL) lo[i] = f2b(v[i] - b2f(hi[i]));
                }
                unsigned short* d = &lds[OFF_B + sfr * LDP + sfc];
                ((uint4*)d)[0] = *(const uint4*)&hi[0];
                ((uint4*)d)[1] = *(const uint4*)&hi[8];
                if constexpr (SPL) {
                    unsigned short* dl = d + OFF_LO;
                    ((uint4*)dl)[0] = *(const uint4*)&lo[0];
                    ((uint4*)dl)[1] = *(const uint4*)&lo[8];
                }
            }
            if constexpr (SPL) {  // A from f32 (x), hi+lo
                const float* g = (const float*)Av + (size_t)(bm + sfr) * lda + k0 + sfc;
                float4 u0 = ((const float4*)g)[0];
                float4 u1 = ((const float4*)g)[1];
                float4 u2 = ((const float4*)g)[2];
                float4 u3 = ((const float4*)g)[3];
                float v[16] = {u0.x,u0.y,u0.z,u0.w, u1.x,u1.y,u1.z,u1.w,
                               u2.x,u2.y,u2.z,u2.w, u3.x,u3.y,u3.z,u3.w};
                unsigned short hi[16], lo[16];
#pragma unroll
                for (int i = 0; i < 16; ++i) {
                    hi[i] = f2b(v[i]);
                    lo[i] = f2b(v[i] - b2f(hi[i]));
                }
                unsigned short* d = &lds[sfr * LDP + sfc];
                ((uint4*)d)[0] = *(const uint4*)&hi[0];
                ((uint4*)d)[1] = *(const uint4*)&hi[8];
                unsigned short* dl = d + OFF_LO;
                ((uint4*)dl)[0] = *(const uint4*)&lo[0];
                ((uint4*)dl)[1] = *(const uint4*)&lo[8];
            } else {              // A bf16 direct
                *(uint4*)&lds[sar * LDP + sac] = *(const uint4*)(Ab + a0 + k0);
                *(uint4*)&lds[(32 + sar) * LDP + sac] = *(const uint4*)(Ab + a1 + k0);
            }
        }
        __syncthreads();
        // ---- prefetch next tile (in flight across MFMA + barrier) ----
        if constexpr (BSRC == 0) {
            if (k0 + BK < Ktot) {
                const int kn = k0 + BK;
                const int ak = (EPI == 0) ? (kn < 4096 ? kn : kn - 4096) : kn;
                const int bk = (EPI == 0) ? (kn < 2048 ? kn : kn - 2048) : kn;
                pA0 = *(const uint4*)(Ab + a0 + ak);
                pA1 = *(const uint4*)(Ab + a1 + ak);
                pB0 = *(const uint4*)(Bb + b0 + bk);
                pB1 = *(const uint4*)(Bb + b1 + bk);
            }
        }
        // ---- MFMA ----
#pragma unroll
        for (int s = 0; s < 2; ++s) {
            const int cc = (s * 4 + kq) << 3;
            bf16x8 aF[2], bF[2];
#pragma unroll
            for (int i = 0; i < 2; ++i)
                aF[i] = *(const bf16x8*)&lds[(wmo + i * 16 + fr) * LDP + cc];
#pragma unroll
            for (int j = 0; j < 2; ++j)
                bF[j] = *(const bf16x8*)&lds[OFF_B + (wno + j * 16 + fr) * LDP + cc];
#pragma unroll
            for (int i = 0; i < 2; ++i)
#pragma unroll
                for (int j = 0; j < 2; ++j)
                    acc[i][j] = __builtin_amdgcn_mfma_f32_16x16x32_bf16(aF[i], bF[j], acc[i][j], 0, 0, 0);
            if constexpr (SPL) {
                bf16x8 aL[2], bL[2];
#pragma unroll
                for (int i = 0; i < 2; ++i)
                    aL[i] = *(const bf16x8*)&lds[OFF_LO + (wmo + i * 16 + fr) * LDP + cc];
#pragma unroll
                for (int i = 0; i < 2; ++i)
#pragma unroll
                    for (int j = 0; j < 2; ++j)
                        acc[i][j] = __builtin_amdgcn_mfma_f32_16x16x32_bf16(aL[i], bF[j], acc[i][j], 0, 0, 0);
#pragma unroll
                for (int j = 0; j < 2; ++j)
                    bL[j] = *(const bf16x8*)&lds[OFF_LO + OFF_B + (wno + j * 16 + fr) * LDP + cc];
#pragma unroll
                for (int i = 0; i < 2; ++i)
#pragma unroll
                    for (int j = 0; j < 2; ++j)
                        acc[i][j] = __builtin_amdgcn_mfma_f32_16x16x32_bf16(aF[i], bL[j], acc[i][j], 0, 0, 0);
            }
        }
        __syncthreads();
    }

    // ---- epilogue: C layout col = lane&15, row = (lane>>4)*4 + reg ----
    const int rowg = (lane >> 4) * 4;
#pragma unroll
    for (int j = 0; j < 2; ++j) {
        const int n = n0 + bn + wno + j * 16 + fr;
        const float bs = bias[n];
        float cpf[8], rwf = 0.0f, s1 = 0.0f;
        if (EPI < 2) {
#pragma unroll
            for (int q = 0; q < 8; ++q) cpf[q] = cp[(size_t)n * 9 + q];
            rwf = rw[n];
        }
        if (EPI == 0) s1 = S1[n];
        const int s = n & 7;  // generator slot: {0,1}->sx, {2,3}->sy, {4..7}->identity
#pragma unroll
        for (int i = 0; i < 2; ++i) {
            const int m0 = bm + wmo + i * 16 + rowg;
#pragma unroll
            for (int r = 0; r < 4; ++r) {
                const int m = m0 + r;
                float v = acc[i][j][r];
                if (EPI == 0) v = (v - mu[m] * s1) * rstd[m] + bs;
                else          v += bs;
                if (EPI < 2) {
                    v = kan_spline(tanhf(v), cpf, rwf);
                    float p = __shfl_xor(v, 1, 64);  // partner col n^1 lives in lane^1
                    p = fminf(fmaxf(p, -1.0f), 1.0f);
                    if (s < 4) v += ((s == 2) ? -0.05f : 0.05f) * p;
                }
                if (EPI == 2) ((float*)outp)[(size_t)m * Nld + n] = v;
                else ((unsigned short*)outp)[(size_t)m * Nld + n] = f2b(v);
            }
        }
    }
}

extern "C" void kernel_launch(void* const* d_in, const int* in_sizes, int n_in,
                              void* d_out, int out_size, void* d_ws, size_t ws_size,
                              hipStream_t stream) {
    const float* x    = (const float*)d_in[0];
    const float* W1   = (const float*)d_in[1];
    const float* b1   = (const float*)d_in[2];
    const float* cp1  = (const float*)d_in[3];
    const float* rw1  = (const float*)d_in[4];
    const float* W2   = (const float*)d_in[5];
    const float* b2   = (const float*)d_in[6];
    const float* cp2  = (const float*)d_in[7];
    const float* rw2  = (const float*)d_in[8];
    const float* W3   = (const float*)d_in[9];
    const float* b3   = (const float*)d_in[10];
    const float* cp3  = (const float*)d_in[11];
    const float* rw3  = (const float*)d_in[12];
    const float* Wout = (const float*)d_in[13];
    const float* bout = (const float*)d_in[14];

    char* ws = (char*)d_ws;
    float* mu   = (float*)(ws);                  // 1024 f32
    float* rstd = (float*)(ws + 4096);           // 1024 f32
    float* S1   = (float*)(ws + 8192);           // 4096 f32
    unsigned short* A2 = (unsigned short*)(ws + 32768);              // 1024x4096 bf16
    unsigned short* A3 = (unsigned short*)(ws + 32768 + 8388608);    // 1024x4096 bf16
    unsigned short* A4 = A2;                      // A2 dead after L2 gemm
    unsigned short* Asplit = A3;                  // x split lives in A3 slot until L2 writes it
    unsigned short* Wb = (unsigned short*)(ws + 32768 + 2 * 8388608);
    const size_t NEED_FULL = 32768 + 2 * 8388608 + 33554432;  // 50.4 MB
    const size_t NEED_HALF = 32768 + 2 * 8388608 + 16777216;  // 33.6 MB

    ln_stats_kernel<<<1024, 256, 0, stream>>>(x, mu, rstd);
    rowsum_kernel<<<1024, 256, 0, stream>>>(W1, S1, 2048);

    if (ws_size >= NEED_FULL) {
        split2_kernel<<<1024, 256, 0, stream>>>(x, Asplit, 2048);
        split2_kernel<<<4096, 256, 0, stream>>>(W1, Wb, 2048);
        gemm_kan<0, 0><<<dim3(16, 64), 256, 0, stream>>>(
            Asplit, Wb, b1, cp1, rw1, mu, rstd, S1, A2, 4096, 0, 6144, 4096, 4096);
        cvt_kernel<<<8192, 256, 0, stream>>>(W2, Wb);
        gemm_kan<1, 0><<<dim3(16, 64), 256, 0, stream>>>(
            A2, Wb, b2, cp2, rw2, nullptr, nullptr, nullptr, A3, 4096, 0, 4096, 4096, 4096);
        cvt_kernel<<<4096, 256, 0, stream>>>(W3, Wb);
        gemm_kan<1, 0><<<dim3(16, 32), 256, 0, stream>>>(
            A3, Wb, b3, cp3, rw3, nullptr, nullptr, nullptr, A4, 2048, 0, 4096, 4096, 4096);
        cvt_kernel<<<2048, 256, 0, stream>>>(Wout, Wb);
        gemm_kan<2, 0><<<dim3(16, 32), 256, 0, stream>>>(
            A4, Wb, bout, nullptr, nullptr, nullptr, nullptr, nullptr, d_out, 2048, 0, 2048, 2048, 2048);
    } else if (ws_size >= NEED_HALF) {
        split2_kernel<<<1024, 256, 0, stream>>>(x, Asplit, 2048);
        for (int h = 0; h < 2; ++h) {
            split2_kernel<<<2048, 256, 0, stream>>>(W1 + (size_t)h * 2048 * 2048, Wb, 2048);
            gemm_kan<0, 0><<<dim3(16, 32), 256, 0, stream>>>(
                Asplit, Wb, b1, cp1, rw1, mu, rstd, S1, A2, 4096, h * 2048, 6144, 4096, 4096);
        }
        for (int h = 0; h < 2; ++h) {
            cvt_kernel<<<4096, 256, 0, stream>>>(W2 + (size_t)h * 2048 * 4096, Wb);
            gemm_kan<1, 0><<<dim3(16, 32), 256, 0, stream>>>(
                A2, Wb, b2, cp2, rw2, nullptr, nullptr, nullptr, A3, 4096, h * 2048, 4096, 4096, 4096);
        }
        cvt_kernel<<<4096, 256, 0, stream>>>(W3, Wb);
        gemm_kan<1, 0><<<dim3(16, 32), 256, 0, stream>>>(
            A3, Wb, b3, cp3, rw3, nullptr, nullptr, nullptr, A4, 2048, 0, 4096, 4096, 4096);
        cvt_kernel<<<2048, 256, 0, stream>>>(Wout, Wb);
        gemm_kan<2, 0><<<dim3(16, 32), 256, 0, stream>>>(
            A4, Wb, bout, nullptr, nullptr, nullptr, nullptr, nullptr, d_out, 2048, 0, 2048, 2048, 2048);
    } else {
        // 16.8 MB insurance path: in-loop conversion (round-4-proven staging)
        gemm_kan<0, 2><<<dim3(16, 64), 256, 0, stream>>>(
            x, W1, b1, cp1, rw1, mu, rstd, S1, A2, 4096, 0, 2048, 2048, 2048);
        gemm_kan<1, 1><<<dim3(16, 64), 256, 0, stream>>>(
            A2, W2, b2, cp2, rw2, nullptr, nullptr, nullptr, A3, 4096, 0, 4096, 4096, 4096);
        gemm_kan<1, 1><<<dim3(16, 32), 256, 0, stream>>>(
            A3, W3, b3, cp3, rw3, nullptr, nullptr, nullptr, A4, 2048, 0, 4096, 4096, 4096);
        gemm_kan<2, 1><<<dim3(16, 32), 256, 0, stream>>>(
            A4, Wout, bout, nullptr, nullptr, nullptr, nullptr, nullptr, d_out, 2048, 0, 2048, 2048, 2048);
    }
}